// Round 2
// baseline (973.464 us; speedup 1.0000x reference)
//
#include <hip/hip_runtime.h>
#include <hip/hip_bf16.h>

// ---- problem constants ----
#define M_IMG 1008
#define N_PCD 1024
#define CDIM  256
#define NI_F  76800
#define NP_F  30000
#define KI    64
#define KP    64
#define NUM_CORR 256
#define NPAIR (NUM_CORR * KI)       // 16384
#define CAND_CAP 4096
#define KEY_MOD 30001u
#define SENT_KEY (76800u * 30001u + 30000u)   // 2,304,106,800 < 2^32

#define NEG_INF (-__builtin_inff())

// bool inputs may arrive as uint8 (numpy bool) or int32 (harness "integer")
// layouts. Detected at runtime; flag==1 means uint8.
__device__ __forceinline__ bool mask_val(const void* p, int i, int is_u8) {
    return is_u8 ? (((const unsigned char*)p)[i] != 0)
                 : (((const int*)p)[i] != 0);
}

// Kernel 0: detect bool layout from pcd_knn_msk (65536 elements, ~90% true).
// Under int32 layout, all bytes at j%4!=0 are exactly 0. grid(1)x256
__global__ void detect_bool_kernel(const unsigned char* __restrict__ p,
                                   int* __restrict__ flag) {
    __shared__ int s_cnt;
    if (threadIdx.x == 0) s_cnt = 0;
    __syncthreads();
    int local = 0;
    for (int j = threadIdx.x; j < 65536; j += 256)
        if ((j & 3) != 0 && p[j] != 0) local++;
    if (local) atomicAdd(&s_cnt, local);
    __syncthreads();
    if (threadIdx.x == 0) *flag = (s_cnt != 0) ? 1 : 0;
}

// =====================================================================
// Kernel A: coarse sim = img_c @ pcd_c^T, masked to -inf.  grid(16,16)x256
// =====================================================================
__global__ void coarse_sim_kernel(const float* __restrict__ A,   // [1008,256]
                                  const float* __restrict__ B,   // [1024,256]
                                  const void* __restrict__ maskA,
                                  const void* __restrict__ maskB,
                                  const int* __restrict__ flag,
                                  float* __restrict__ sim) {     // [1008,1024]
    __shared__ float sa[64][33];
    __shared__ float sb[64][33];
    const int is_u8 = *flag;
    const int m0 = blockIdx.y * 64, n0 = blockIdx.x * 64;
    const int tid = threadIdx.x;
    const int ki = tid >> 2;            // row within tile 0..63
    const int kpb = (tid & 3) << 4;     // col group base 0/16/32/48
    float acc[16];
#pragma unroll
    for (int j = 0; j < 16; j++) acc[j] = 0.f;

    for (int cc = 0; cc < CDIM; cc += 32) {
        for (int e = tid; e < 64 * 32; e += 256) {
            int r = e >> 5, c = e & 31;
            int m = m0 + r;
            sa[r][c] = A[(m < M_IMG ? m : 0) * CDIM + cc + c];
            sb[r][c] = B[(n0 + r) * CDIM + cc + c];
        }
        __syncthreads();
#pragma unroll
        for (int c = 0; c < 32; c++) {
            float a = sa[ki][c];
#pragma unroll
            for (int j = 0; j < 16; j++) acc[j] += a * sb[kpb + j][c];
        }
        __syncthreads();
    }
    int m = m0 + ki;
    if (m < M_IMG) {
        bool ma = mask_val(maskA, m, is_u8);
#pragma unroll
        for (int j = 0; j < 16; j++) {
            int n = n0 + kpb + j;
            bool ok = ma && mask_val(maskB, n, is_u8);
            sim[m * N_PCD + n] = ok ? acc[j] : NEG_INF;
        }
    }
}

// ---- top-3 helpers (values only, multiplicity preserved) ----
__device__ __forceinline__ void top3_insert(float v, float& t0, float& t1, float& t2) {
    if (v > t0) { t2 = t1; t1 = t0; t0 = v; }
    else if (v > t1) { t2 = t1; t1 = v; }
    else if (v > t2) { t2 = v; }
}

__device__ __forceinline__ void top3_block_reduce(float t0, float t1, float t2,
                                                  float* kth_out) {
    __shared__ float st[256][3];
    int tid = threadIdx.x;
    st[tid][0] = t0; st[tid][1] = t1; st[tid][2] = t2;
    __syncthreads();
    for (int s = 128; s > 0; s >>= 1) {
        if (tid < s) {
            float a0 = st[tid][0], a1 = st[tid][1], a2 = st[tid][2];
            float b0 = st[tid + s][0], b1 = st[tid + s][1], b2 = st[tid + s][2];
            float x0, x1, x2;
            if (a0 >= b0) {
                x0 = a0;
                if (a1 >= b0) { x1 = a1; x2 = (a2 >= b0) ? a2 : b0; }
                else          { x1 = b0; x2 = (a1 >= b1) ? a1 : b1; }
            } else {
                x0 = b0;
                if (b1 >= a0) { x1 = b1; x2 = (b2 >= a0) ? b2 : a0; }
                else          { x1 = a0; x2 = (b1 >= a1) ? b1 : a1; }
            }
            st[tid][0] = x0; st[tid][1] = x1; st[tid][2] = x2;
        }
        __syncthreads();
    }
    if (tid == 0) *kth_out = st[0][2];
}

// Kernel B: per-row 3rd largest. grid(1008)x256
__global__ void row_kth_kernel(const float* __restrict__ sim, float* __restrict__ row_kth) {
    const float* r = sim + (size_t)blockIdx.x * N_PCD;
    float t0 = NEG_INF, t1 = NEG_INF, t2 = NEG_INF;
    for (int e = threadIdx.x; e < N_PCD; e += 256) top3_insert(r[e], t0, t1, t2);
    top3_block_reduce(t0, t1, t2, &row_kth[blockIdx.x]);
}

// Kernel C: per-col 3rd largest. grid(1024)x256
__global__ void col_kth_kernel(const float* __restrict__ sim, float* __restrict__ col_kth) {
    const float* c = sim + blockIdx.x;
    float t0 = NEG_INF, t1 = NEG_INF, t2 = NEG_INF;
    for (int e = threadIdx.x; e < M_IMG; e += 256) top3_insert(c[(size_t)e * N_PCD], t0, t1, t2);
    top3_block_reduce(t0, t1, t2, &col_kth[blockIdx.x]);
}

// Kernel D: compact mutual candidates. grid(4032)x256
__global__ void compact_kernel(const float* __restrict__ sim,
                               const float* __restrict__ row_kth,
                               const float* __restrict__ col_kth,
                               unsigned long long* __restrict__ cand,
                               int* __restrict__ count) {
    int g = blockIdx.x * 256 + threadIdx.x;
    if (g >= M_IMG * N_PCD) return;
    int m = g >> 10, n = g & 1023;
    float v = sim[g];
    if (v > 0.f && v >= row_kth[m] && v >= col_kth[n]) {
        int pos = atomicAdd(count, 1);
        if (pos < CAND_CAP) {
            unsigned int u = __float_as_uint(v);
            unsigned int mono = (u & 0x80000000u) ? ~u : (u | 0x80000000u); // ascending map
            cand[pos] = ((unsigned long long)(~mono) << 32) | (unsigned int)g; // asc sort => val desc, idx asc
        }
    }
}

// Kernel E: top-256 by bitonic sort of <=4096 packed candidates. grid(1)x256
__global__ void top256_kernel(const unsigned long long* __restrict__ cand,
                              const int* __restrict__ count,
                              int* __restrict__ sel_idx,
                              int* __restrict__ selK) {
    __shared__ unsigned long long s[CAND_CAP];
    int tid = threadIdx.x;
    int K = *count; if (K > CAND_CAP) K = CAND_CAP;
    for (int e = tid; e < CAND_CAP; e += 256)
        s[e] = (e < K) ? cand[e] : 0xFFFFFFFFFFFFFFFFull;
    __syncthreads();
    for (int k = 2; k <= CAND_CAP; k <<= 1) {
        for (int j = k >> 1; j > 0; j >>= 1) {
            for (int i = tid; i < CAND_CAP; i += 256) {
                int ij = i ^ j;
                if (ij > i) {
                    bool up = ((i & k) == 0);
                    unsigned long long a = s[i], b = s[ij];
                    if ((a > b) == up) { s[i] = b; s[ij] = a; }
                }
            }
            __syncthreads();
        }
    }
    if (tid < NUM_CORR) sel_idx[tid] = (int)(s[tid] & 0xFFFFFFFFull);
    if (tid == 0) *selK = (K < NUM_CORR) ? K : NUM_CORR;
}

// =====================================================================
// Kernel F: fine matching, one block per correspondence. grid(256)x256
// =====================================================================
__global__ void fine_kernel(const float* __restrict__ img_f,   // [76800,256]
                            const float* __restrict__ pcd_f,   // [30000,256]
                            const int* __restrict__ img_knn,   // [1008,64]
                            const int* __restrict__ pcd_knn,   // [1024,64]
                            const void* __restrict__ pcd_msk,  // [1024,64] bool
                            const int* __restrict__ flag,
                            const int* __restrict__ sel_idx,
                            const int* __restrict__ selK_ptr,
                            unsigned int* __restrict__ keys) { // [16384]
    const int ci = blockIdx.x, tid = threadIdx.x;
    const int selK = *selK_ptr;
    if (ci >= selK) {
        if (tid < KI) keys[ci * KI + tid] = SENT_KEY;
        return;
    }
    __shared__ int s_ik[KI], s_pk[KP];
    __shared__ unsigned char s_mk[KP];
    __shared__ float s_a[64][33], s_b[64][33];
    __shared__ float s_sim[64][65];
    __shared__ int s_rb[64], s_cb[64];
    __shared__ float s_rv[64];

    int flat = sel_idx[ci];
    int gi = flat >> 10, pi = flat & 1023;
    if (tid < 64) {
        const int is_u8 = *flag;
        s_ik[tid] = img_knn[gi * KI + tid];
        s_pk[tid] = pcd_knn[pi * KP + tid];
        s_mk[tid] = mask_val(pcd_msk, pi * KP + tid, is_u8) ? 1 : 0;
    }
    __syncthreads();

    const int ki = tid >> 2, kpb = (tid & 3) << 4;
    float acc[16];
#pragma unroll
    for (int j = 0; j < 16; j++) acc[j] = 0.f;

    for (int cc = 0; cc < CDIM; cc += 32) {
        for (int e = tid; e < 64 * 32; e += 256) {
            int r = e >> 5, c = e & 31;
            s_a[r][c] = img_f[(size_t)s_ik[r] * CDIM + cc + c];
            s_b[r][c] = pcd_f[(size_t)s_pk[r] * CDIM + cc + c];
        }
        __syncthreads();
#pragma unroll
        for (int c = 0; c < 32; c++) {
            float a = s_a[ki][c];
#pragma unroll
            for (int j = 0; j < 16; j++) acc[j] += a * s_b[kpb + j][c];
        }
        __syncthreads();
    }
#pragma unroll
    for (int j = 0; j < 16; j++) {
        int kp = kpb + j;
        s_sim[ki][kp] = (s_mk[kp] != 0) ? acc[j] : NEG_INF;
    }
    __syncthreads();

    if (tid < 64) {              // row argmax over kp (first-max semantics)
        float best = NEG_INF; int bi = 0;
        for (int kp = 0; kp < 64; kp++) {
            float v = s_sim[tid][kp];
            if (v > best) { best = v; bi = kp; }
        }
        s_rb[tid] = bi; s_rv[tid] = best;
    } else if (tid < 128) {      // col argmax over ki
        int kp = tid - 64;
        float best = NEG_INF; int bi = 0;
        for (int k2 = 0; k2 < 64; k2++) {
            float v = s_sim[k2][kp];
            if (v > best) { best = v; bi = k2; }
        }
        s_cb[kp] = bi;
    }
    __syncthreads();

    if (tid < 64) {
        int rb = s_rb[tid];
        float rv = s_rv[tid];
        bool sel = (s_cb[rb] == tid) && (rv > 0.f);   // mutual top-1 + finite + >FINE_THR
        unsigned int key = sel
            ? ((unsigned int)s_ik[tid] * KEY_MOD + (unsigned int)s_pk[rb])
            : SENT_KEY;
        keys[ci * KI + tid] = key;
    }
}

// =====================================================================
// Kernel G: rank (stable-sort position) + first-occurrence + score.
// grid(64)x256.  out[rank_i] = first_i && ic<NI_F ? dot(img[ic],pcd[pc]) : 0
// =====================================================================
__global__ void rank_kernel(const unsigned int* __restrict__ keys,
                            const float* __restrict__ img_f,
                            const float* __restrict__ pcd_f,
                            float* __restrict__ out) {
    __shared__ unsigned int s_k[4096];
    const int tid = threadIdx.x;
    const int i = blockIdx.x * 256 + tid;
    const unsigned int myKey = keys[i];
    int less = 0, eqb = 0;
    for (int ch = 0; ch < 4; ch++) {
        for (int e = tid; e < 4096; e += 256) s_k[e] = keys[ch * 4096 + e];
        __syncthreads();
        int base = ch * 4096;
        for (int j = 0; j < 4096; j++) {
            unsigned int k = s_k[j];
            less += (k < myKey);
            eqb += (k == myKey && (base + j) < i);
        }
        __syncthreads();
    }
    int rank = less + eqb;
    unsigned int ic = myKey / KEY_MOD;
    unsigned int pc = myKey - ic * KEY_MOD;
    float score = 0.f;
    if (eqb == 0 && ic < (unsigned)NI_F) {
        const float4* a = (const float4*)(img_f + (size_t)ic * CDIM);
        const float4* b = (const float4*)(pcd_f + (size_t)pc * CDIM);
        float s = 0.f;
#pragma unroll 4
        for (int c = 0; c < CDIM / 4; c++) {
            float4 x = a[c], y = b[c];
            s += x.x * y.x + x.y * y.y + x.z * y.z + x.w * y.w;
        }
        score = s;
    }
    out[rank] = score;
}

// =====================================================================
extern "C" void kernel_launch(void* const* d_in, const int* in_sizes, int n_in,
                              void* d_out, int out_size, void* d_ws, size_t ws_size,
                              hipStream_t stream) {
    const float* img_c = (const float*)d_in[0];
    const float* pcd_c = (const float*)d_in[1];
    const float* img_f = (const float*)d_in[2];
    const float* pcd_f = (const float*)d_in[3];
    const void* img_mask = d_in[4];
    const void* pcd_mask = d_in[5];
    const int* img_knn = (const int*)d_in[6];
    const int* pcd_knn = (const int*)d_in[7];
    const void* pcd_knn_msk = d_in[8];
    float* out = (float*)d_out;

    // ---- workspace layout ----
    char* w = (char*)d_ws;
    size_t off = 0;
    float* sim = (float*)(w + off);            off += (size_t)M_IMG * N_PCD * 4; // 4,128,768
    float* row_kth = (float*)(w + off);        off += M_IMG * 4;
    float* col_kth = (float*)(w + off);        off += N_PCD * 4;
    int* count = (int*)(w + off);              off += 4;
    int* selK = (int*)(w + off);               off += 4;
    int* boolflag = (int*)(w + off);           off += 4;
    off = (off + 7) & ~(size_t)7;
    unsigned long long* cand = (unsigned long long*)(w + off); off += CAND_CAP * 8;
    int* sel_idx = (int*)(w + off);            off += NUM_CORR * 4;
    unsigned int* keys = (unsigned int*)(w + off); off += NPAIR * 4;

    hipMemsetAsync(count, 0, 8, stream);  // zero count + selK

    detect_bool_kernel<<<1, 256, 0, stream>>>((const unsigned char*)pcd_knn_msk, boolflag);
    coarse_sim_kernel<<<dim3(16, 16), 256, 0, stream>>>(img_c, pcd_c, img_mask, pcd_mask,
                                                        boolflag, sim);
    row_kth_kernel<<<M_IMG, 256, 0, stream>>>(sim, row_kth);
    col_kth_kernel<<<N_PCD, 256, 0, stream>>>(sim, col_kth);
    compact_kernel<<<(M_IMG * N_PCD) / 256, 256, 0, stream>>>(sim, row_kth, col_kth, cand, count);
    top256_kernel<<<1, 256, 0, stream>>>(cand, count, sel_idx, selK);
    fine_kernel<<<NUM_CORR, 256, 0, stream>>>(img_f, pcd_f, img_knn, pcd_knn, pcd_knn_msk,
                                              boolflag, sel_idx, selK, keys);
    rank_kernel<<<NPAIR / 256, 256, 0, stream>>>(keys, img_f, pcd_f, out);
}

// Round 3
// 570.391 us; speedup vs baseline: 1.7067x; 1.7067x over previous
//
#include <hip/hip_runtime.h>
#include <hip/hip_bf16.h>

// ---- problem constants ----
#define M_IMG 1008
#define N_PCD 1024
#define CDIM  256
#define NI_F  76800
#define NP_F  30000
#define KI    64
#define KP    64
#define NUM_CORR 256
#define NPAIR (NUM_CORR * KI)       // 16384
#define CAND_CAP 4096
#define KEY_MOD 30001u
#define SENT_KEY (76800u * 30001u + 30000u)   // 2,304,106,800 < 2^32

#define NEG_INF (-__builtin_inff())

// bool inputs may arrive as uint8 (numpy bool) or int32 (harness "integer")
// layouts. Detected at runtime; flag==1 means uint8.
__device__ __forceinline__ bool mask_val(const void* p, int i, int is_u8) {
    return is_u8 ? (((const unsigned char*)p)[i] != 0)
                 : (((const int*)p)[i] != 0);
}

// Kernel 0: detect bool layout from pcd_knn_msk (65536 elements, ~90% true).
// Under int32 layout, all bytes at j%4!=0 are exactly 0. grid(1)x256
__global__ void detect_bool_kernel(const unsigned char* __restrict__ p,
                                   int* __restrict__ flag) {
    __shared__ int s_cnt;
    if (threadIdx.x == 0) s_cnt = 0;
    __syncthreads();
    int local = 0;
    for (int j = threadIdx.x; j < 65536; j += 256)
        if ((j & 3) != 0 && p[j] != 0) local++;
    if (local) atomicAdd(&s_cnt, local);
    __syncthreads();
    if (threadIdx.x == 0) *flag = (s_cnt != 0) ? 1 : 0;
}

// =====================================================================
// Kernel A: coarse sim = img_c @ pcd_c^T, masked to -inf.  grid(16,16)x256
// =====================================================================
__global__ void coarse_sim_kernel(const float* __restrict__ A,   // [1008,256]
                                  const float* __restrict__ B,   // [1024,256]
                                  const void* __restrict__ maskA,
                                  const void* __restrict__ maskB,
                                  const int* __restrict__ flag,
                                  float* __restrict__ sim) {     // [1008,1024]
    __shared__ float sa[64][33];
    __shared__ float sb[64][33];
    const int is_u8 = *flag;
    const int m0 = blockIdx.y * 64, n0 = blockIdx.x * 64;
    const int tid = threadIdx.x;
    const int ki = tid >> 2;            // row within tile 0..63
    const int kpb = (tid & 3) << 4;     // col group base 0/16/32/48
    float acc[16];
#pragma unroll
    for (int j = 0; j < 16; j++) acc[j] = 0.f;

    for (int cc = 0; cc < CDIM; cc += 32) {
        for (int e = tid; e < 64 * 32; e += 256) {
            int r = e >> 5, c = e & 31;
            int m = m0 + r;
            sa[r][c] = A[(m < M_IMG ? m : 0) * CDIM + cc + c];
            sb[r][c] = B[(n0 + r) * CDIM + cc + c];
        }
        __syncthreads();
#pragma unroll
        for (int c = 0; c < 32; c++) {
            float a = sa[ki][c];
#pragma unroll
            for (int j = 0; j < 16; j++) acc[j] += a * sb[kpb + j][c];
        }
        __syncthreads();
    }
    int m = m0 + ki;
    if (m < M_IMG) {
        bool ma = mask_val(maskA, m, is_u8);
#pragma unroll
        for (int j = 0; j < 16; j++) {
            int n = n0 + kpb + j;
            bool ok = ma && mask_val(maskB, n, is_u8);
            sim[m * N_PCD + n] = ok ? acc[j] : NEG_INF;
        }
    }
}

// ---- top-3 helpers (values only, multiplicity preserved) ----
__device__ __forceinline__ void top3_insert(float v, float& t0, float& t1, float& t2) {
    if (v > t0) { t2 = t1; t1 = t0; t0 = v; }
    else if (v > t1) { t2 = t1; t1 = v; }
    else if (v > t2) { t2 = v; }
}

__device__ __forceinline__ void top3_block_reduce(float t0, float t1, float t2,
                                                  float* kth_out) {
    __shared__ float st[256][3];
    int tid = threadIdx.x;
    st[tid][0] = t0; st[tid][1] = t1; st[tid][2] = t2;
    __syncthreads();
    for (int s = 128; s > 0; s >>= 1) {
        if (tid < s) {
            float a0 = st[tid][0], a1 = st[tid][1], a2 = st[tid][2];
            float b0 = st[tid + s][0], b1 = st[tid + s][1], b2 = st[tid + s][2];
            float x0, x1, x2;
            if (a0 >= b0) {
                x0 = a0;
                if (a1 >= b0) { x1 = a1; x2 = (a2 >= b0) ? a2 : b0; }
                else          { x1 = b0; x2 = (a1 >= b1) ? a1 : b1; }
            } else {
                x0 = b0;
                if (b1 >= a0) { x1 = b1; x2 = (b2 >= a0) ? b2 : a0; }
                else          { x1 = a0; x2 = (b1 >= a1) ? b1 : a1; }
            }
            st[tid][0] = x0; st[tid][1] = x1; st[tid][2] = x2;
        }
        __syncthreads();
    }
    if (tid == 0) *kth_out = st[0][2];
}

// Kernel B: per-row 3rd largest. grid(1008)x256
__global__ void row_kth_kernel(const float* __restrict__ sim, float* __restrict__ row_kth) {
    const float* r = sim + (size_t)blockIdx.x * N_PCD;
    float t0 = NEG_INF, t1 = NEG_INF, t2 = NEG_INF;
    for (int e = threadIdx.x; e < N_PCD; e += 256) top3_insert(r[e], t0, t1, t2);
    top3_block_reduce(t0, t1, t2, &row_kth[blockIdx.x]);
}

// Kernel C: per-col 3rd largest. grid(1024)x256
__global__ void col_kth_kernel(const float* __restrict__ sim, float* __restrict__ col_kth) {
    const float* c = sim + blockIdx.x;
    float t0 = NEG_INF, t1 = NEG_INF, t2 = NEG_INF;
    for (int e = threadIdx.x; e < M_IMG; e += 256) top3_insert(c[(size_t)e * N_PCD], t0, t1, t2);
    top3_block_reduce(t0, t1, t2, &col_kth[blockIdx.x]);
}

// Kernel D: compact mutual candidates. grid(4032)x256
__global__ void compact_kernel(const float* __restrict__ sim,
                               const float* __restrict__ row_kth,
                               const float* __restrict__ col_kth,
                               unsigned long long* __restrict__ cand,
                               int* __restrict__ count) {
    int g = blockIdx.x * 256 + threadIdx.x;
    if (g >= M_IMG * N_PCD) return;
    int m = g >> 10, n = g & 1023;
    float v = sim[g];
    if (v > 0.f && v >= row_kth[m] && v >= col_kth[n]) {
        int pos = atomicAdd(count, 1);
        if (pos < CAND_CAP) {
            unsigned int u = __float_as_uint(v);
            unsigned int mono = (u & 0x80000000u) ? ~u : (u | 0x80000000u); // ascending map
            cand[pos] = ((unsigned long long)(~mono) << 32) | (unsigned int)g; // asc sort => val desc, idx asc
        }
    }
}

// Kernel E: top-256 by bitonic sort of <=4096 packed candidates. grid(1)x256
__global__ void top256_kernel(const unsigned long long* __restrict__ cand,
                              const int* __restrict__ count,
                              int* __restrict__ sel_idx,
                              int* __restrict__ selK) {
    __shared__ unsigned long long s[CAND_CAP];
    int tid = threadIdx.x;
    int K = *count; if (K > CAND_CAP) K = CAND_CAP;
    for (int e = tid; e < CAND_CAP; e += 256)
        s[e] = (e < K) ? cand[e] : 0xFFFFFFFFFFFFFFFFull;
    __syncthreads();
    for (int k = 2; k <= CAND_CAP; k <<= 1) {
        for (int j = k >> 1; j > 0; j >>= 1) {
            for (int i = tid; i < CAND_CAP; i += 256) {
                int ij = i ^ j;
                if (ij > i) {
                    bool up = ((i & k) == 0);
                    unsigned long long a = s[i], b = s[ij];
                    if ((a > b) == up) { s[i] = b; s[ij] = a; }
                }
            }
            __syncthreads();
        }
    }
    if (tid < NUM_CORR) sel_idx[tid] = (int)(s[tid] & 0xFFFFFFFFull);
    if (tid == 0) *selK = (K < NUM_CORR) ? K : NUM_CORR;
}

// =====================================================================
// Kernel F: fine matching, one block per correspondence. grid(256)x256
// =====================================================================
__global__ void fine_kernel(const float* __restrict__ img_f,   // [76800,256]
                            const float* __restrict__ pcd_f,   // [30000,256]
                            const int* __restrict__ img_knn,   // [1008,64]
                            const int* __restrict__ pcd_knn,   // [1024,64]
                            const void* __restrict__ pcd_msk,  // [1024,64] bool
                            const int* __restrict__ flag,
                            const int* __restrict__ sel_idx,
                            const int* __restrict__ selK_ptr,
                            unsigned int* __restrict__ keys) { // [16384]
    const int ci = blockIdx.x, tid = threadIdx.x;
    const int selK = *selK_ptr;
    if (ci >= selK) {
        if (tid < KI) keys[ci * KI + tid] = SENT_KEY;
        return;
    }
    __shared__ int s_ik[KI], s_pk[KP];
    __shared__ unsigned char s_mk[KP];
    __shared__ float s_a[64][33], s_b[64][33];
    __shared__ float s_sim[64][65];
    __shared__ int s_rb[64], s_cb[64];
    __shared__ float s_rv[64];

    int flat = sel_idx[ci];
    int gi = flat >> 10, pi = flat & 1023;
    if (tid < 64) {
        const int is_u8 = *flag;
        s_ik[tid] = img_knn[gi * KI + tid];
        s_pk[tid] = pcd_knn[pi * KP + tid];
        s_mk[tid] = mask_val(pcd_msk, pi * KP + tid, is_u8) ? 1 : 0;
    }
    __syncthreads();

    const int ki = tid >> 2, kpb = (tid & 3) << 4;
    float acc[16];
#pragma unroll
    for (int j = 0; j < 16; j++) acc[j] = 0.f;

    for (int cc = 0; cc < CDIM; cc += 32) {
        for (int e = tid; e < 64 * 32; e += 256) {
            int r = e >> 5, c = e & 31;
            s_a[r][c] = img_f[(size_t)s_ik[r] * CDIM + cc + c];
            s_b[r][c] = pcd_f[(size_t)s_pk[r] * CDIM + cc + c];
        }
        __syncthreads();
#pragma unroll
        for (int c = 0; c < 32; c++) {
            float a = s_a[ki][c];
#pragma unroll
            for (int j = 0; j < 16; j++) acc[j] += a * s_b[kpb + j][c];
        }
        __syncthreads();
    }
#pragma unroll
    for (int j = 0; j < 16; j++) {
        int kp = kpb + j;
        s_sim[ki][kp] = (s_mk[kp] != 0) ? acc[j] : NEG_INF;
    }
    __syncthreads();

    if (tid < 64) {              // row argmax over kp (first-max semantics)
        float best = NEG_INF; int bi = 0;
        for (int kp = 0; kp < 64; kp++) {
            float v = s_sim[tid][kp];
            if (v > best) { best = v; bi = kp; }
        }
        s_rb[tid] = bi; s_rv[tid] = best;
    } else if (tid < 128) {      // col argmax over ki
        int kp = tid - 64;
        float best = NEG_INF; int bi = 0;
        for (int k2 = 0; k2 < 64; k2++) {
            float v = s_sim[k2][kp];
            if (v > best) { best = v; bi = k2; }
        }
        s_cb[kp] = bi;
    }
    __syncthreads();

    if (tid < 64) {
        int rb = s_rb[tid];
        float rv = s_rv[tid];
        bool sel = (s_cb[rb] == tid) && (rv > 0.f);   // mutual top-1 + finite + >FINE_THR
        unsigned int key = sel
            ? ((unsigned int)s_ik[tid] * KEY_MOD + (unsigned int)s_pk[rb])
            : SENT_KEY;
        keys[ci * KI + tid] = key;
    }
}

// =====================================================================
// Kernel G1: chunked rank partial counts. grid(64 my, 64 other)x256.
// cnt[i] += (less<<16) | eq_before  (packed u32; field totals < 2^16)
// =====================================================================
__global__ void rank_count_kernel(const unsigned int* __restrict__ keys,
                                  unsigned int* __restrict__ cnt) {
    __shared__ unsigned int s_k[256];
    const int tid = threadIdx.x;
    const int bi = blockIdx.x, bj = blockIdx.y;
    const int i = bi * 256 + tid;
    const unsigned int myKey = keys[i];
    s_k[tid] = keys[bj * 256 + tid];
    __syncthreads();

    unsigned int less = 0, eqb = 0;
    if (bj < bi) {
#pragma unroll 8
        for (int j = 0; j < 256; j++) {
            unsigned int k = s_k[j];
            less += (k < myKey);
            eqb += (k == myKey);
        }
    } else if (bj == bi) {
#pragma unroll 8
        for (int j = 0; j < 256; j++) {
            unsigned int k = s_k[j];
            less += (k < myKey);
            eqb += (k == myKey) & (j < tid);
        }
    } else {
#pragma unroll 8
        for (int j = 0; j < 256; j++) {
            unsigned int k = s_k[j];
            less += (k < myKey);
        }
    }
    atomicAdd(&cnt[i], (less << 16) | eqb);
}

// Kernel G2: unpack rank, first-occurrence; write scored output. grid(64)x256
__global__ void rank_out_kernel(const unsigned int* __restrict__ keys,
                                const unsigned int* __restrict__ cnt,
                                const float* __restrict__ img_f,
                                const float* __restrict__ pcd_f,
                                float* __restrict__ out) {
    const int i = blockIdx.x * 256 + threadIdx.x;
    const unsigned int myKey = keys[i];
    const unsigned int v = cnt[i];
    const int rank = (int)(v >> 16) + (int)(v & 0xFFFFu);
    unsigned int ic = myKey / KEY_MOD;
    unsigned int pc = myKey - ic * KEY_MOD;
    float score = 0.f;
    if ((v & 0xFFFFu) == 0 && ic < (unsigned)NI_F) {
        const float4* a = (const float4*)(img_f + (size_t)ic * CDIM);
        const float4* b = (const float4*)(pcd_f + (size_t)pc * CDIM);
        float s = 0.f;
#pragma unroll 4
        for (int c = 0; c < CDIM / 4; c++) {
            float4 x = a[c], y = b[c];
            s += x.x * y.x + x.y * y.y + x.z * y.z + x.w * y.w;
        }
        score = s;
    }
    out[rank] = score;
}

// =====================================================================
extern "C" void kernel_launch(void* const* d_in, const int* in_sizes, int n_in,
                              void* d_out, int out_size, void* d_ws, size_t ws_size,
                              hipStream_t stream) {
    const float* img_c = (const float*)d_in[0];
    const float* pcd_c = (const float*)d_in[1];
    const float* img_f = (const float*)d_in[2];
    const float* pcd_f = (const float*)d_in[3];
    const void* img_mask = d_in[4];
    const void* pcd_mask = d_in[5];
    const int* img_knn = (const int*)d_in[6];
    const int* pcd_knn = (const int*)d_in[7];
    const void* pcd_knn_msk = d_in[8];
    float* out = (float*)d_out;

    // ---- workspace layout ----
    char* w = (char*)d_ws;
    size_t off = 0;
    float* sim = (float*)(w + off);            off += (size_t)M_IMG * N_PCD * 4; // 4,128,768
    float* row_kth = (float*)(w + off);        off += M_IMG * 4;
    float* col_kth = (float*)(w + off);        off += N_PCD * 4;
    int* count = (int*)(w + off);              off += 4;
    int* selK = (int*)(w + off);               off += 4;
    int* boolflag = (int*)(w + off);           off += 4;
    off = (off + 7) & ~(size_t)7;
    unsigned long long* cand = (unsigned long long*)(w + off); off += CAND_CAP * 8;
    int* sel_idx = (int*)(w + off);            off += NUM_CORR * 4;
    unsigned int* keys = (unsigned int*)(w + off); off += NPAIR * 4;
    unsigned int* cnt = (unsigned int*)(w + off);  off += NPAIR * 4;

    hipMemsetAsync(count, 0, 8, stream);       // zero count + selK
    hipMemsetAsync(cnt, 0, NPAIR * 4, stream); // zero rank counters

    detect_bool_kernel<<<1, 256, 0, stream>>>((const unsigned char*)pcd_knn_msk, boolflag);
    coarse_sim_kernel<<<dim3(16, 16), 256, 0, stream>>>(img_c, pcd_c, img_mask, pcd_mask,
                                                        boolflag, sim);
    row_kth_kernel<<<M_IMG, 256, 0, stream>>>(sim, row_kth);
    col_kth_kernel<<<N_PCD, 256, 0, stream>>>(sim, col_kth);
    compact_kernel<<<(M_IMG * N_PCD) / 256, 256, 0, stream>>>(sim, row_kth, col_kth, cand, count);
    top256_kernel<<<1, 256, 0, stream>>>(cand, count, sel_idx, selK);
    fine_kernel<<<NUM_CORR, 256, 0, stream>>>(img_f, pcd_f, img_knn, pcd_knn, pcd_knn_msk,
                                              boolflag, sel_idx, selK, keys);
    rank_count_kernel<<<dim3(64, 64), 256, 0, stream>>>(keys, cnt);
    rank_out_kernel<<<NPAIR / 256, 256, 0, stream>>>(keys, cnt, img_f, pcd_f, out);
}